// Round 16
// baseline (163.436 us; speedup 1.0000x reference)
//
#include <hip/hip_runtime.h>
#include <hip/hip_bf16.h>

#define B 4
#define S 2048
#define H 16
#define D 64
#define HID 1024

typedef __hip_bfloat16 bf16;
typedef __attribute__((ext_vector_type(8))) short bf16x8;
typedef __attribute__((ext_vector_type(4))) short bf16x4;
typedef __attribute__((ext_vector_type(4))) float f32x4;

static __device__ __forceinline__ float b2f(bf16 v) { return __bfloat162float(v); }

static __device__ __forceinline__ unsigned pkbf(float a, float b) {
    union { bf16 h; unsigned short u; } ua, ub;
    ua.h = __float2bfloat16(a);
    ub.h = __float2bfloat16(b);
    return (unsigned)ua.u | ((unsigned)ub.u << 16);
}

#define SCL 0.18033688011112042f   // 0.125 * log2(e), folded into Q at projection

// ---------------------------------------------------------------------------
// Kernel 1: QKV projection — R27 body (best-proven).
// Q/K: swapped MFMA operands + DIRECT global store epilogue. V: LDS transpose.
// ---------------------------------------------------------------------------
#define QSTR 72
#define VTS  132   // repack stride: (VTS/2)%4 != 0 -> quad rows hit disjoint banks

__global__ __launch_bounds__(256) void qkv_mfma_kernel(
    const float* __restrict__ x,
    const float* __restrict__ Wq, const float* __restrict__ bq,
    const float* __restrict__ Wk, const float* __restrict__ bk,
    const float* __restrict__ Wv, const float* __restrict__ bv,
    bf16* __restrict__ q, bf16* __restrict__ k, bf16* __restrict__ v)
{
    __shared__ __align__(16) char smem[36864];  // Xs+Wt; V reuses for T
    __shared__ float bs[128];
    bf16* Xs = (bf16*)smem;
    bf16* Wt = (bf16*)(smem + 128 * QSTR * 2);

    const int tid = threadIdx.x;
    const int mat = blockIdx.y >> 3;
    const int N0  = (blockIdx.y & 7) * 128;
    const int m0  = blockIdx.x * 128;

    const float* W    = (mat == 0) ? Wq : (mat == 1) ? Wk : Wv;
    const float* bias = (mat == 0) ? bq : (mat == 1) ? bk : bv;
    bf16*        dst  = (mat == 0) ? q  : (mat == 1) ? k  : v;
    const float  oscale = (mat == 0) ? SCL : 1.0f;

    #pragma unroll
    for (int i = 0; i < 8; ++i) {
        int item = i * 256 + tid;
        int row = item >> 4, f4 = item & 15;
        float4 xv = *(const float4*)&x[(size_t)(m0 + row) * D + f4 * 4];
        union { bf16 h[4]; bf16x4 v4; } u;
        u.h[0] = __float2bfloat16(xv.x); u.h[1] = __float2bfloat16(xv.y);
        u.h[2] = __float2bfloat16(xv.z); u.h[3] = __float2bfloat16(xv.w);
        *(bf16x4*)&Xs[row * QSTR + f4 * 4] = u.v4;
    }
    #pragma unroll
    for (int i = 0; i < 2; ++i) {
        int unit = i * 256 + tid;
        int n0 = (unit & 31) * 4, k0 = (unit >> 5) * 4;
        float wv[4][4];
        #pragma unroll
        for (int j = 0; j < 4; ++j) {
            float4 t = *(const float4*)&W[(size_t)(k0 + j) * HID + N0 + n0];
            wv[j][0] = t.x; wv[j][1] = t.y; wv[j][2] = t.z; wv[j][3] = t.w;
        }
        #pragma unroll
        for (int dn = 0; dn < 4; ++dn) {
            union { bf16 h[4]; bf16x4 v4; } u;
            #pragma unroll
            for (int j = 0; j < 4; ++j) u.h[j] = __float2bfloat16(wv[j][dn]);
            *(bf16x4*)&Wt[(n0 + dn) * QSTR + k0] = u.v4;
        }
    }
    if (tid < 128) bs[tid] = bias[N0 + tid];
    __syncthreads();

    const int lane = tid & 63, wave = tid >> 6;
    const int c = lane & 15, quad = lane >> 4;

    bf16x8 af[2][2];
    #pragma unroll
    for (int mg = 0; mg < 2; ++mg)
        #pragma unroll
        for (int kc = 0; kc < 2; ++kc)
            af[mg][kc] = *(const bf16x8*)&Xs[(wave * 32 + mg * 16 + c) * QSTR + kc * 32 + quad * 8];

    f32x4 acc[2][8];
    #pragma unroll
    for (int mg = 0; mg < 2; ++mg)
        #pragma unroll
        for (int ng = 0; ng < 8; ++ng)
            acc[mg][ng] = (f32x4){0.f, 0.f, 0.f, 0.f};

    const int b_ = m0 >> 11, ss0 = m0 & (S - 1);

    if (mat == 2) {
        // V: original orientation — D col<->n, row<->m (feeds [hid][ss] transpose)
        #pragma unroll
        for (int ng = 0; ng < 8; ++ng) {
            bf16x8 bf0 = *(const bf16x8*)&Wt[(ng * 16 + c) * QSTR + quad * 8];
            bf16x8 bf1 = *(const bf16x8*)&Wt[(ng * 16 + c) * QSTR + 32 + quad * 8];
            #pragma unroll
            for (int mg = 0; mg < 2; ++mg) {
                acc[mg][ng] = __builtin_amdgcn_mfma_f32_16x16x32_bf16(af[mg][0], bf0, acc[mg][ng], 0, 0, 0);
                acc[mg][ng] = __builtin_amdgcn_mfma_f32_16x16x32_bf16(af[mg][1], bf1, acc[mg][ng], 0, 0, 0);
            }
        }
        // ---- V: in-LDS transpose T[hid][ss] -> coalesced [B][H][D][S] ----
        bf16* T = (bf16*)smem;            // 128 x VTS bf16
        __syncthreads();
        #pragma unroll
        for (int ng = 0; ng < 8; ++ng) {
            int hid_l = ng * 16 + c;
            float bb_ = bs[hid_l];
            #pragma unroll
            for (int mg = 0; mg < 2; ++mg) {
                int ss_l = wave * 32 + mg * 16 + quad * 4;
                union { bf16 h4[4]; bf16x4 v4; } u;
                #pragma unroll
                for (int r = 0; r < 4; ++r)
                    u.h4[r] = __float2bfloat16(acc[mg][ng][r] + bb_);
                *(bf16x4*)&T[hid_l * VTS + ss_l] = u.v4;
            }
        }
        __syncthreads();
        #pragma unroll
        for (int pass = 0; pass < 8; ++pass) {
            int unit = pass * 256 + tid;
            int dd_l = unit >> 4, u8 = unit & 15;
            bf16x8 val = *(const bf16x8*)&T[dd_l * VTS + u8 * 8];
            int h = (N0 >> 6) + (dd_l >> 6), ddg = dd_l & 63;
            *(bf16x8*)&dst[((size_t)(b_ * H + h) * D + ddg) * S + ss0 + u8 * 8] = val;
        }
    } else {
        // Q/K: SWAPPED operands — D row<->n, col<->m
        #pragma unroll
        for (int ng = 0; ng < 8; ++ng) {
            bf16x8 bf0 = *(const bf16x8*)&Wt[(ng * 16 + c) * QSTR + quad * 8];
            bf16x8 bf1 = *(const bf16x8*)&Wt[(ng * 16 + c) * QSTR + 32 + quad * 8];
            #pragma unroll
            for (int mg = 0; mg < 2; ++mg) {
                acc[mg][ng] = __builtin_amdgcn_mfma_f32_16x16x32_bf16(bf0, af[mg][0], acc[mg][ng], 0, 0, 0);
                acc[mg][ng] = __builtin_amdgcn_mfma_f32_16x16x32_bf16(bf1, af[mg][1], acc[mg][ng], 0, 0, 0);
            }
        }
        // ---- Q/K: DIRECT global store (no T2, no extra barrier) ----
        #pragma unroll
        for (int ng = 0; ng < 8; ++ng) {
            float4 bb4 = *(const float4*)&bs[ng * 16 + quad * 4];
            int n_g = N0 + ng * 16 + quad * 4;
            int h = n_g >> 6, dd = n_g & 63;
            #pragma unroll
            for (int mg = 0; mg < 2; ++mg) {
                int mrow = wave * 32 + mg * 16 + c;
                union { bf16 h4[4]; bf16x4 v4; } u;
                #pragma unroll
                for (int r = 0; r < 4; ++r)
                    u.h4[r] = __float2bfloat16((acc[mg][ng][r] + (&bb4.x)[r]) * oscale);
                *(bf16x4*)&dst[((size_t)(b_ * H + h) * S + ss0 + mrow) * D + dd] = u.v4;
            }
        }
    }
}

// ---------------------------------------------------------------------------
// Kernel 2: flash causal attention — R32: DUAL-P ordering on R29 geometry.
// R29/R31 structure kept (8-wave/512-thread, single-barrier dbuf, reg
// staging, u=slot&7 phase-interleave). ONE change: restore R16's dual-P
// schedule front(B); front(A); drain; pv(B); pv(A) — R20 bundled the dbuf
// win with a single-P buffer that forced front;drain;pv;front;drain;pv
// (two drains per dual iteration, each stalling on just-issued P writes).
// Never isolated. Dual P buffers (PsB+PsA, 32KB): ONE drain per iteration,
// front(A)'s 4 MFMA + 16 exp2 fill the P(B)-write->pv(B)-read latency,
// and pv(B)+pv(A) issue as one 16-MFMA burst. LDS 48->64KB — not binding
// (grid caps at 2 blocks/CU; 64KB still fits 2). Watch VGPR (>84 = the
// extra P-state ate the win, R22 lesson).
// ---------------------------------------------------------------------------
#define BT   64
#define NT   (S / BT)   // 32

__global__ __launch_bounds__(512) void flash_mfma_kernel(
    const bf16* __restrict__ qg, const bf16* __restrict__ kg,
    const bf16* __restrict__ vg, bf16* __restrict__ og)
{
    __shared__ bf16 Ks[2][BT * 64];     // K tiles [krow][d-granule swz], dbuf
    __shared__ bf16 Vt[2][BT * 64];     // V^T tiles [d][s-granule swz], dbuf
    __shared__ bf16 PsB[8][16 * 64];    // per-wave P, tile B (swz)
    __shared__ bf16 PsA[8][16 * 64];    // per-wave P, tile A (swz)

    const int tid  = threadIdx.x;
    const int wave = tid >> 6;          // 0..7
    const int lane = tid & 63;
    const int c    = lane & 15;
    const int quad = lane >> 4;
    const int wg   = wave >> 2;         // tile-pair group 0/1
    const int wl   = wave & 3;          // wave within group

    const int L    = (int)blockIdx.x + 8 * (int)blockIdx.y;  // 0..511
    const int xcd  = L & 7;
    const int slot = L >> 3;            // 0..63
    const int u    = slot & 7;          // pair-group index 0..7 (R29 mapping)
    const int bh   = xcd * 8 + (slot >> 3);
    const int b_   = bh >> 4, h_ = bh & 15;
    const size_t hbase = (size_t)bh * S * D;
    bf16* myPB = &PsB[wave][0];
    bf16* myPA = &PsA[wave][0];
    const int srow = wl * 16 + c;       // row within my group's tiles

    const int qta    = 2 * u + wg;          // 0..15
    const int qtb    = 31 - 2 * u - wg;     // 16..31
    const int qtbmax = 31 - 2 * u;          // loop bound (group 0's B-tile)

    // staging: 512 threads, ONE 16B granule each for K and V
    const int sr = tid >> 3, g0 = tid & 7;         // row 0..63, granule 0..7
    const int sc0 = g0 * 8;                        // source column (elements)
    const int so  = sr * 64 + ((g0 ^ (sr & 7)) << 3);  // swizzled LDS offset
    const int cx7 = c & 7;                         // read-side swizzle key

    bf16x8 qfa0, qfa1, qfb0, qfb1;
    {
        const size_t ra = hbase + (size_t)(qta * BT + srow) * D;
        const size_t rb = hbase + (size_t)(qtb * BT + srow) * D;
        qfa0 = *(const bf16x8*)(qg + ra + quad * 8);
        qfa1 = *(const bf16x8*)(qg + ra + 32 + quad * 8);
        qfb0 = *(const bf16x8*)(qg + rb + quad * 8);
        qfb1 = *(const bf16x8*)(qg + rb + 32 + quad * 8);
    }

    float la = 0.f, lb = 0.f;
    f32x4 ota[4], otb[4];
    #pragma unroll
    for (int jn = 0; jn < 4; ++jn) {
        ota[jn] = (f32x4){0.f, 0.f, 0.f, 0.f};
        otb[jn] = (f32x4){0.f, 0.f, 0.f, 0.f};
    }

    auto front = [&](const bf16* Kb, bf16x8 qf0, bf16x8 qf1, bf16* Pdst,
                     float& l1, bool diag) {
        f32x4 st[4];
        #pragma unroll
        for (int jn = 0; jn < 4; ++jn) {
            const int rb_ = (jn * 16 + c) * 64;
            bf16x8 kf0 = *(const bf16x8*)&Kb[rb_ + ((quad       ^ cx7) << 3)];
            bf16x8 kf1 = *(const bf16x8*)&Kb[rb_ + (((quad + 4) ^ cx7) << 3)];
            f32x4 s = {0.f, 0.f, 0.f, 0.f};
            s = __builtin_amdgcn_mfma_f32_16x16x32_bf16(kf0, qf0, s, 0, 0, 0);
            s = __builtin_amdgcn_mfma_f32_16x16x32_bf16(kf1, qf1, s, 0, 0, 0);
            st[jn] = s;
        }
        #pragma unroll
        for (int jn = 0; jn < 4; ++jn) {
            float p0 = __builtin_amdgcn_exp2f(st[jn][0]);
            float p1 = __builtin_amdgcn_exp2f(st[jn][1]);
            float p2 = __builtin_amdgcn_exp2f(st[jn][2]);
            float p3 = __builtin_amdgcn_exp2f(st[jn][3]);
            if (diag) {
                int col = jn * 16 + quad * 4;
                if (col     > srow) p0 = 0.f;
                if (col + 1 > srow) p1 = 0.f;
                if (col + 2 > srow) p2 = 0.f;
                if (col + 3 > srow) p3 = 0.f;
            }
            l1 += (p0 + p1) + (p2 + p3);
            uint2 pk;
            pk.x = pkbf(p0, p1);
            pk.y = pkbf(p2, p3);
            // row c, source granule 2*jn + (quad>>1), 8B half (quad&1)
            *(uint2*)&Pdst[c * 64 + (((2 * jn + (quad >> 1)) ^ cx7) << 3) + (quad & 1) * 4] = pk;
        }
    };
    auto pv = [&](const bf16* Vb, const bf16* Psrc, f32x4* ot) {
        #pragma unroll
        for (int kc = 0; kc < 2; ++kc) {
            bf16x8 pf = *(const bf16x8*)&Psrc[c * 64 + (((kc * 4 + quad) ^ cx7) << 3)];
            #pragma unroll
            for (int jn = 0; jn < 4; ++jn) {
                const int rb_ = (jn * 16 + c) * 64;
                bf16x8 vf = *(const bf16x8*)&Vb[rb_ + (((kc * 4 + quad) ^ cx7) << 3)];
                ot[jn] = __builtin_amdgcn_mfma_f32_16x16x32_bf16(vf, pf, ot[jn], 0, 0, 0);
            }
        }
    };

    // ---- prologue: stage tile 0 into buf 0, prefetch tile 1 into regs ----
    bf16x8 kreg, vreg;
    kreg = *(const bf16x8*)(kg + hbase + (size_t)sr * D + sc0);
    vreg = *(const bf16x8*)(vg + hbase + (size_t)sr * S + sc0);
    *(bf16x8*)&Ks[0][so] = kreg;
    *(bf16x8*)&Vt[0][so] = vreg;
    {   // tile 1 (qtbmax >= 17 always, so it exists)
        const int nb = BT;
        kreg = *(const bf16x8*)(kg + hbase + (size_t)(nb + sr) * D + sc0);
        vreg = *(const bf16x8*)(vg + hbase + (size_t)sr * S + nb + sc0);
    }
    __syncthreads();

    int cur = 0;
    for (int kt = 0; kt <= qtbmax; ++kt) {
        // stage next tile into the buffer freed at the previous barrier,
        // then refill regs with tile kt+2 (latency covered by compute below)
        if (kt < qtbmax) {
            *(bf16x8*)&Ks[cur ^ 1][so] = kreg;
            *(bf16x8*)&Vt[cur ^ 1][so] = vreg;
            if (kt + 1 < qtbmax) {
                const int nb = (kt + 2) * BT;
                kreg = *(const bf16x8*)(kg + hbase + (size_t)(nb + sr) * D + sc0);
                vreg = *(const bf16x8*)(vg + hbase + (size_t)sr * S + nb + sc0);
            }
        }

        const bf16* Kb = &Ks[cur][0];
        const bf16* Vb = &Vt[cur][0];
        if (kt <= qtb) {                 // wave-group-uniform
            const bool withA = (kt <= qta);
            front(Kb, qfb0, qfb1, myPB, lb, kt == qtb);
            if (withA) front(Kb, qfa0, qfa1, myPA, la, kt == qta);
            asm volatile("s_waitcnt lgkmcnt(0)" ::: "memory");  // P writes visible
            pv(Vb, myPB, otb);
            if (withA) pv(Vb, myPA, ota);
        }

        if (kt < qtbmax) {               // block-uniform condition
            __syncthreads();
            cur ^= 1;
        }
    }

    {
        float lt = lb;
        lt += __shfl_xor(lt, 16);
        lt += __shfl_xor(lt, 32);
        const float inv = 1.f / lt;
        const size_t obase = ((size_t)(b_ * S + qtb * BT + srow)) * HID + h_ * 64 + quad * 4;
        #pragma unroll
        for (int jn = 0; jn < 4; ++jn) {
            union { bf16 h4[4]; bf16x4 v4; } u;
            #pragma unroll
            for (int r = 0; r < 4; ++r)
                u.h4[r] = __float2bfloat16(otb[jn][r] * inv);
            *(bf16x4*)&og[obase + jn * 16] = u.v4;
        }
    }
    {
        float lt = la;
        lt += __shfl_xor(lt, 16);
        lt += __shfl_xor(lt, 32);
        const float inv = 1.f / lt;
        const size_t obase = ((size_t)(b_ * S + qta * BT + srow)) * HID + h_ * 64 + quad * 4;
        #pragma unroll
        for (int jn = 0; jn < 4; ++jn) {
            union { bf16 h4[4]; bf16x4 v4; } u;
            #pragma unroll
            for (int r = 0; r < 4; ++r)
                u.h4[r] = __float2bfloat16(ota[jn][r] * inv);
            *(bf16x4*)&og[obase + jn * 16] = u.v4;
        }
    }
}

// ---------------------------------------------------------------------------
// Kernel 3: output projection — R25 dbuf body (kept).
// ---------------------------------------------------------------------------
__global__ __launch_bounds__(256) void out_proj_mfma_kernel(
    const bf16* __restrict__ o, const float* __restrict__ Wo,
    const float* __restrict__ bo, float* __restrict__ out)
{
    __shared__ bf16 Os[2][32 * QSTR];
    __shared__ bf16 Wot[2][64 * QSTR];
    __shared__ float bos[64];

    const int tid = threadIdx.x;
    const int m0  = blockIdx.x * 32;
    const int lane = tid & 63, wave = tid >> 6;
    const int c = lane & 15, quad = lane >> 4;
    const int mtile = wave >> 1;
    const int ngb   = (wave & 1) * 2;

    const int orow = tid >> 3, ooct = tid & 7;
    const int n0 = (tid & 15) * 4, kk0 = (tid >> 4) * 4;

    if (tid < 64) bos[tid] = bo[tid];

    bf16x8 oreg = *(const bf16x8*)(o + (size_t)(m0 + orow) * HID + ooct * 8);
    float4 w4[4];
    #pragma unroll
    for (int j = 0; j < 4; ++j)
        w4[j] = *(const float4*)&Wo[(size_t)(kk0 + j) * 64 + n0];

    auto stage = [&](int buf) {
        *(bf16x8*)&Os[buf][orow * QSTR + ooct * 8] = oreg;
        #pragma unroll
        for (int dn = 0; dn < 4; ++dn) {
            union { bf16 h[4]; bf16x4 v4; } u;
            u.h[0] = __float2bfloat16((&w4[0].x)[dn]);
            u.h[1] = __float2bfloat16((&w4[1].x)[dn]);
            u.h[2] = __float2bfloat16((&w4[2].x)[dn]);
            u.h[3] = __float2bfloat16((&w4[3].x)[dn]);
            *(bf16x4*)&Wot[buf][(n0 + dn) * QSTR + kk0] = u.v4;
        }
    };

    // prologue: stage chunk 0 into buf 0, prefetch chunk 1 into regs
    stage(0);
    {
        const int k1 = 64;
        oreg = *(const bf16x8*)(o + (size_t)(m0 + orow) * HID + k1 + ooct * 8);
        #pragma unroll
        for (int j = 0; j < 4; ++j)
            w4[j] = *(const float4*)&Wo[(size_t)(k1 + kk0 + j) * 64 + n0];
    }
    __syncthreads();

    f32x4 acc[2];
    acc[0] = (f32x4){0.f, 0.f, 0.f, 0.f};
    acc[1] = (f32x4){0.f, 0.f, 0.f, 0.f};

    int cur = 0;
    for (int chunk = 0; chunk < 16; ++chunk) {
        // stage next chunk into the freed buffer, refill regs with chunk+2
        if (chunk < 15) {
            stage(cur ^ 1);
            if (chunk + 1 < 15) {
                const int k2 = (chunk + 2) * 64;
                oreg = *(const bf16x8*)(o + (size_t)(m0 + orow) * HID + k2 + ooct * 8);
                #pragma unroll
                for (int j = 0; j < 4; ++j)
                    w4[j] = *(const float4*)&Wo[(size_t)(k2 + kk0 + j) * 64 + n0];
            }
        }

        bf16x8 a0 = *(const bf16x8*)&Os[cur][(mtile * 16 + c) * QSTR + quad * 8];
        bf16x8 a1 = *(const bf16x8*)&Os[cur][(mtile * 16 + c) * QSTR + 32 + quad * 8];
        #pragma unroll
        for (int g = 0; g < 2; ++g) {
            int ng = ngb + g;
            bf16x8 b0 = *(const bf16x8*)&Wot[cur][(ng * 16 + c) * QSTR + quad * 8];
            bf16x8 b1 = *(const bf16x8*)&Wot[cur][(ng * 16 + c) * QSTR + 32 + quad * 8];
            acc[g] = __builtin_amdgcn_mfma_f32_16x16x32_bf16(a0, b0, acc[g], 0, 0, 0);
            acc[g] = __builtin_amdgcn_mfma_f32_16x16x32_bf16(a1, b1, acc[g], 0, 0, 0);
        }

        if (chunk < 15) {
            __syncthreads();
            cur ^= 1;
        }
    }

    #pragma unroll
    for (int g = 0; g < 2; ++g) {
        int n = (ngb + g) * 16 + c;
        float bb_ = bos[n];
        #pragma unroll
        for (int r = 0; r < 4; ++r) {
            int row = m0 + mtile * 16 + quad * 4 + r;
            out[(size_t)row * 64 + n] = acc[g][r] + bb_;
        }
    }
}

// ---------------------------------------------------------------------------
extern "C" void kernel_launch(void* const* d_in, const int* in_sizes, int n_in,
                              void* d_out, int out_size, void* d_ws, size_t ws_size,
                              hipStream_t stream)
{
    const float* x  = (const float*)d_in[0];
    const float* Wq = (const float*)d_in[1];
    const float* bq = (const float*)d_in[2];
    const float* Wk = (const float*)d_in[3];
    const float* bk = (const float*)d_in[4];
    const float* Wv = (const float*)d_in[5];
    const float* bv = (const float*)d_in[6];
    const float* Wo = (const float*)d_in[7];
    const float* bo = (const float*)d_in[8];

    char* ws = (char*)d_ws;
    const size_t qkv_bytes = (size_t)B * S * HID * sizeof(bf16);  // 16 MiB each
    bf16* qw = (bf16*)(ws);
    bf16* kw = (bf16*)(ws + qkv_bytes);
    bf16* vw = (bf16*)(ws + 2 * qkv_bytes);   // transposed [B][H][D][S]
    bf16* ow = (bf16*)(ws + 3 * qkv_bytes);

    qkv_mfma_kernel<<<dim3(B * S / 128, 24), 256, 0, stream>>>(
        x, Wq, bq, Wk, bk, Wv, bv, qw, kw, vw);

    flash_mfma_kernel<<<dim3(8, B * H), 512, 0, stream>>>(qw, kw, vw, ow);

    out_proj_mfma_kernel<<<dim3(B * S / 32), 256, 0, stream>>>(ow, Wo, bo,
                                                               (float*)d_out);
}

// Round 17
// 152.481 us; speedup vs baseline: 1.0718x; 1.0718x over previous
//
#include <hip/hip_runtime.h>
#include <hip/hip_bf16.h>

#define B 4
#define S 2048
#define H 16
#define D 64
#define HID 1024

typedef __hip_bfloat16 bf16;
typedef __attribute__((ext_vector_type(8))) short bf16x8;
typedef __attribute__((ext_vector_type(4))) short bf16x4;
typedef __attribute__((ext_vector_type(4))) float f32x4;

static __device__ __forceinline__ float b2f(bf16 v) { return __bfloat162float(v); }

static __device__ __forceinline__ unsigned pkbf(float a, float b) {
    union { bf16 h; unsigned short u; } ua, ub;
    ua.h = __float2bfloat16(a);
    ub.h = __float2bfloat16(b);
    return (unsigned)ua.u | ((unsigned)ub.u << 16);
}

#define SCL 0.18033688011112042f   // 0.125 * log2(e), folded into Q at projection

// ---------------------------------------------------------------------------
// Kernel 1: QKV projection — R27 body (best-proven).
// Q/K: swapped MFMA operands + DIRECT global store epilogue. V: LDS transpose.
// ---------------------------------------------------------------------------
#define QSTR 72
#define VTS  132   // repack stride: (VTS/2)%4 != 0 -> quad rows hit disjoint banks

__global__ __launch_bounds__(256) void qkv_mfma_kernel(
    const float* __restrict__ x,
    const float* __restrict__ Wq, const float* __restrict__ bq,
    const float* __restrict__ Wk, const float* __restrict__ bk,
    const float* __restrict__ Wv, const float* __restrict__ bv,
    bf16* __restrict__ q, bf16* __restrict__ k, bf16* __restrict__ v)
{
    __shared__ __align__(16) char smem[36864];  // Xs+Wt; V reuses for T
    __shared__ float bs[128];
    bf16* Xs = (bf16*)smem;
    bf16* Wt = (bf16*)(smem + 128 * QSTR * 2);

    const int tid = threadIdx.x;
    const int mat = blockIdx.y >> 3;
    const int N0  = (blockIdx.y & 7) * 128;
    const int m0  = blockIdx.x * 128;

    const float* W    = (mat == 0) ? Wq : (mat == 1) ? Wk : Wv;
    const float* bias = (mat == 0) ? bq : (mat == 1) ? bk : bv;
    bf16*        dst  = (mat == 0) ? q  : (mat == 1) ? k  : v;
    const float  oscale = (mat == 0) ? SCL : 1.0f;

    #pragma unroll
    for (int i = 0; i < 8; ++i) {
        int item = i * 256 + tid;
        int row = item >> 4, f4 = item & 15;
        float4 xv = *(const float4*)&x[(size_t)(m0 + row) * D + f4 * 4];
        union { bf16 h[4]; bf16x4 v4; } u;
        u.h[0] = __float2bfloat16(xv.x); u.h[1] = __float2bfloat16(xv.y);
        u.h[2] = __float2bfloat16(xv.z); u.h[3] = __float2bfloat16(xv.w);
        *(bf16x4*)&Xs[row * QSTR + f4 * 4] = u.v4;
    }
    #pragma unroll
    for (int i = 0; i < 2; ++i) {
        int unit = i * 256 + tid;
        int n0 = (unit & 31) * 4, k0 = (unit >> 5) * 4;
        float wv[4][4];
        #pragma unroll
        for (int j = 0; j < 4; ++j) {
            float4 t = *(const float4*)&W[(size_t)(k0 + j) * HID + N0 + n0];
            wv[j][0] = t.x; wv[j][1] = t.y; wv[j][2] = t.z; wv[j][3] = t.w;
        }
        #pragma unroll
        for (int dn = 0; dn < 4; ++dn) {
            union { bf16 h[4]; bf16x4 v4; } u;
            #pragma unroll
            for (int j = 0; j < 4; ++j) u.h[j] = __float2bfloat16(wv[j][dn]);
            *(bf16x4*)&Wt[(n0 + dn) * QSTR + k0] = u.v4;
        }
    }
    if (tid < 128) bs[tid] = bias[N0 + tid];
    __syncthreads();

    const int lane = tid & 63, wave = tid >> 6;
    const int c = lane & 15, quad = lane >> 4;

    bf16x8 af[2][2];
    #pragma unroll
    for (int mg = 0; mg < 2; ++mg)
        #pragma unroll
        for (int kc = 0; kc < 2; ++kc)
            af[mg][kc] = *(const bf16x8*)&Xs[(wave * 32 + mg * 16 + c) * QSTR + kc * 32 + quad * 8];

    f32x4 acc[2][8];
    #pragma unroll
    for (int mg = 0; mg < 2; ++mg)
        #pragma unroll
        for (int ng = 0; ng < 8; ++ng)
            acc[mg][ng] = (f32x4){0.f, 0.f, 0.f, 0.f};

    const int b_ = m0 >> 11, ss0 = m0 & (S - 1);

    if (mat == 2) {
        // V: original orientation — D col<->n, row<->m (feeds [hid][ss] transpose)
        #pragma unroll
        for (int ng = 0; ng < 8; ++ng) {
            bf16x8 bf0 = *(const bf16x8*)&Wt[(ng * 16 + c) * QSTR + quad * 8];
            bf16x8 bf1 = *(const bf16x8*)&Wt[(ng * 16 + c) * QSTR + 32 + quad * 8];
            #pragma unroll
            for (int mg = 0; mg < 2; ++mg) {
                acc[mg][ng] = __builtin_amdgcn_mfma_f32_16x16x32_bf16(af[mg][0], bf0, acc[mg][ng], 0, 0, 0);
                acc[mg][ng] = __builtin_amdgcn_mfma_f32_16x16x32_bf16(af[mg][1], bf1, acc[mg][ng], 0, 0, 0);
            }
        }
        // ---- V: in-LDS transpose T[hid][ss] -> coalesced [B][H][D][S] ----
        bf16* T = (bf16*)smem;            // 128 x VTS bf16
        __syncthreads();
        #pragma unroll
        for (int ng = 0; ng < 8; ++ng) {
            int hid_l = ng * 16 + c;
            float bb_ = bs[hid_l];
            #pragma unroll
            for (int mg = 0; mg < 2; ++mg) {
                int ss_l = wave * 32 + mg * 16 + quad * 4;
                union { bf16 h4[4]; bf16x4 v4; } u;
                #pragma unroll
                for (int r = 0; r < 4; ++r)
                    u.h4[r] = __float2bfloat16(acc[mg][ng][r] + bb_);
                *(bf16x4*)&T[hid_l * VTS + ss_l] = u.v4;
            }
        }
        __syncthreads();
        #pragma unroll
        for (int pass = 0; pass < 8; ++pass) {
            int unit = pass * 256 + tid;
            int dd_l = unit >> 4, u8 = unit & 15;
            bf16x8 val = *(const bf16x8*)&T[dd_l * VTS + u8 * 8];
            int h = (N0 >> 6) + (dd_l >> 6), ddg = dd_l & 63;
            *(bf16x8*)&dst[((size_t)(b_ * H + h) * D + ddg) * S + ss0 + u8 * 8] = val;
        }
    } else {
        // Q/K: SWAPPED operands — D row<->n, col<->m
        #pragma unroll
        for (int ng = 0; ng < 8; ++ng) {
            bf16x8 bf0 = *(const bf16x8*)&Wt[(ng * 16 + c) * QSTR + quad * 8];
            bf16x8 bf1 = *(const bf16x8*)&Wt[(ng * 16 + c) * QSTR + 32 + quad * 8];
            #pragma unroll
            for (int mg = 0; mg < 2; ++mg) {
                acc[mg][ng] = __builtin_amdgcn_mfma_f32_16x16x32_bf16(bf0, af[mg][0], acc[mg][ng], 0, 0, 0);
                acc[mg][ng] = __builtin_amdgcn_mfma_f32_16x16x32_bf16(bf1, af[mg][1], acc[mg][ng], 0, 0, 0);
            }
        }
        // ---- Q/K: DIRECT global store (no T2, no extra barrier) ----
        #pragma unroll
        for (int ng = 0; ng < 8; ++ng) {
            float4 bb4 = *(const float4*)&bs[ng * 16 + quad * 4];
            int n_g = N0 + ng * 16 + quad * 4;
            int h = n_g >> 6, dd = n_g & 63;
            #pragma unroll
            for (int mg = 0; mg < 2; ++mg) {
                int mrow = wave * 32 + mg * 16 + c;
                union { bf16 h4[4]; bf16x4 v4; } u;
                #pragma unroll
                for (int r = 0; r < 4; ++r)
                    u.h4[r] = __float2bfloat16((acc[mg][ng][r] + (&bb4.x)[r]) * oscale);
                *(bf16x4*)&dst[((size_t)(b_ * H + h) * S + ss0 + mrow) * D + dd] = u.v4;
            }
        }
    }
}

// ---------------------------------------------------------------------------
// Kernel 2: flash causal attention — R29/R31 body, FINAL (60.8-61.2us,
// quadruple-reproduced). Structure: 8-wave/512-thread blocks (2/CU), wave-
// group g owns constant-work pair (2u+g, 31-2u-g) with u=slot&7 phase-
// interleave (LJF remap regressed: FETCH up, R30); single-barrier double-
// buffered K/V staging in regs (global_load_lds regressed: depth-1 pipeline,
// R28); single P buffer per wave (dual-P regressed: 64KB LDS + 72 VGPR
// collapsed occupancy 31->19%, R32); manual lgkmcnt(0) P-drains (removing
// them raised VGPR 84->100, R22; drain stalls are covered by co-resident
// waves); no setprio (R19: -4%).
// ---------------------------------------------------------------------------
#define BT   64
#define NT   (S / BT)   // 32

__global__ __launch_bounds__(512) void flash_mfma_kernel(
    const bf16* __restrict__ qg, const bf16* __restrict__ kg,
    const bf16* __restrict__ vg, bf16* __restrict__ og)
{
    __shared__ bf16 Ks[2][BT * 64];     // K tiles [krow][d-granule swz], dbuf
    __shared__ bf16 Vt[2][BT * 64];     // V^T tiles [d][s-granule swz], dbuf
    __shared__ bf16 Ps[8][16 * 64];     // per-wave P (single buffer, swz)

    const int tid  = threadIdx.x;
    const int wave = tid >> 6;          // 0..7
    const int lane = tid & 63;
    const int c    = lane & 15;
    const int quad = lane >> 4;
    const int wg   = wave >> 2;         // tile-pair group 0/1
    const int wl   = wave & 3;          // wave within group

    const int L    = (int)blockIdx.x + 8 * (int)blockIdx.y;  // 0..511
    const int xcd  = L & 7;
    const int slot = L >> 3;            // 0..63
    const int u    = slot & 7;          // pair-group index 0..7 (R29 mapping)
    const int bh   = xcd * 8 + (slot >> 3);
    const int b_   = bh >> 4, h_ = bh & 15;
    const size_t hbase = (size_t)bh * S * D;
    bf16* myP = &Ps[wave][0];
    const int srow = wl * 16 + c;       // row within my group's tiles

    const int qta    = 2 * u + wg;          // 0..15
    const int qtb    = 31 - 2 * u - wg;     // 16..31
    const int qtbmax = 31 - 2 * u;          // loop bound (group 0's B-tile)

    // staging: 512 threads, ONE 16B granule each for K and V
    const int sr = tid >> 3, g0 = tid & 7;         // row 0..63, granule 0..7
    const int sc0 = g0 * 8;                        // source column (elements)
    const int so  = sr * 64 + ((g0 ^ (sr & 7)) << 3);  // swizzled LDS offset
    const int cx7 = c & 7;                         // read-side swizzle key

    bf16x8 qfa0, qfa1, qfb0, qfb1;
    {
        const size_t ra = hbase + (size_t)(qta * BT + srow) * D;
        const size_t rb = hbase + (size_t)(qtb * BT + srow) * D;
        qfa0 = *(const bf16x8*)(qg + ra + quad * 8);
        qfa1 = *(const bf16x8*)(qg + ra + 32 + quad * 8);
        qfb0 = *(const bf16x8*)(qg + rb + quad * 8);
        qfb1 = *(const bf16x8*)(qg + rb + 32 + quad * 8);
    }

    float la = 0.f, lb = 0.f;
    f32x4 ota[4], otb[4];
    #pragma unroll
    for (int jn = 0; jn < 4; ++jn) {
        ota[jn] = (f32x4){0.f, 0.f, 0.f, 0.f};
        otb[jn] = (f32x4){0.f, 0.f, 0.f, 0.f};
    }

    auto front = [&](const bf16* Kb, bf16x8 qf0, bf16x8 qf1, float& l1, bool diag) {
        f32x4 st[4];
        #pragma unroll
        for (int jn = 0; jn < 4; ++jn) {
            const int rb_ = (jn * 16 + c) * 64;
            bf16x8 kf0 = *(const bf16x8*)&Kb[rb_ + ((quad       ^ cx7) << 3)];
            bf16x8 kf1 = *(const bf16x8*)&Kb[rb_ + (((quad + 4) ^ cx7) << 3)];
            f32x4 s = {0.f, 0.f, 0.f, 0.f};
            s = __builtin_amdgcn_mfma_f32_16x16x32_bf16(kf0, qf0, s, 0, 0, 0);
            s = __builtin_amdgcn_mfma_f32_16x16x32_bf16(kf1, qf1, s, 0, 0, 0);
            st[jn] = s;
        }
        #pragma unroll
        for (int jn = 0; jn < 4; ++jn) {
            float p0 = __builtin_amdgcn_exp2f(st[jn][0]);
            float p1 = __builtin_amdgcn_exp2f(st[jn][1]);
            float p2 = __builtin_amdgcn_exp2f(st[jn][2]);
            float p3 = __builtin_amdgcn_exp2f(st[jn][3]);
            if (diag) {
                int col = jn * 16 + quad * 4;
                if (col     > srow) p0 = 0.f;
                if (col + 1 > srow) p1 = 0.f;
                if (col + 2 > srow) p2 = 0.f;
                if (col + 3 > srow) p3 = 0.f;
            }
            l1 += (p0 + p1) + (p2 + p3);
            uint2 pk;
            pk.x = pkbf(p0, p1);
            pk.y = pkbf(p2, p3);
            // row c, source granule 2*jn + (quad>>1), 8B half (quad&1)
            *(uint2*)&myP[c * 64 + (((2 * jn + (quad >> 1)) ^ cx7) << 3) + (quad & 1) * 4] = pk;
        }
    };
    auto pv = [&](const bf16* Vb, f32x4* ot) {
        #pragma unroll
        for (int kc = 0; kc < 2; ++kc) {
            bf16x8 pf = *(const bf16x8*)&myP[c * 64 + (((kc * 4 + quad) ^ cx7) << 3)];
            #pragma unroll
            for (int jn = 0; jn < 4; ++jn) {
                const int rb_ = (jn * 16 + c) * 64;
                bf16x8 vf = *(const bf16x8*)&Vb[rb_ + (((kc * 4 + quad) ^ cx7) << 3)];
                ot[jn] = __builtin_amdgcn_mfma_f32_16x16x32_bf16(vf, pf, ot[jn], 0, 0, 0);
            }
        }
    };

    // ---- prologue: stage tile 0 into buf 0, prefetch tile 1 into regs ----
    bf16x8 kreg, vreg;
    kreg = *(const bf16x8*)(kg + hbase + (size_t)sr * D + sc0);
    vreg = *(const bf16x8*)(vg + hbase + (size_t)sr * S + sc0);
    *(bf16x8*)&Ks[0][so] = kreg;
    *(bf16x8*)&Vt[0][so] = vreg;
    {   // tile 1 (qtbmax >= 17 always, so it exists)
        const int nb = BT;
        kreg = *(const bf16x8*)(kg + hbase + (size_t)(nb + sr) * D + sc0);
        vreg = *(const bf16x8*)(vg + hbase + (size_t)sr * S + nb + sc0);
    }
    __syncthreads();

    int cur = 0;
    for (int kt = 0; kt <= qtbmax; ++kt) {
        // stage next tile into the buffer freed at the previous barrier,
        // then refill regs with tile kt+2 (latency covered by compute below)
        if (kt < qtbmax) {
            *(bf16x8*)&Ks[cur ^ 1][so] = kreg;
            *(bf16x8*)&Vt[cur ^ 1][so] = vreg;
            if (kt + 1 < qtbmax) {
                const int nb = (kt + 2) * BT;
                kreg = *(const bf16x8*)(kg + hbase + (size_t)(nb + sr) * D + sc0);
                vreg = *(const bf16x8*)(vg + hbase + (size_t)sr * S + nb + sc0);
            }
        }

        const bf16* Kb = &Ks[cur][0];
        const bf16* Vb = &Vt[cur][0];
        if (kt <= qtb) {                 // wave-group-uniform
            front(Kb, qfb0, qfb1, lb, kt == qtb);
            asm volatile("s_waitcnt lgkmcnt(0)" ::: "memory");  // P writes visible
            pv(Vb, otb);
        }
        if (kt <= qta) {                 // wave-group-uniform
            front(Kb, qfa0, qfa1, la, kt == qta);
            asm volatile("s_waitcnt lgkmcnt(0)" ::: "memory");
            pv(Vb, ota);
        }

        if (kt < qtbmax) {               // block-uniform condition
            __syncthreads();
            cur ^= 1;
        }
    }

    {
        float lt = lb;
        lt += __shfl_xor(lt, 16);
        lt += __shfl_xor(lt, 32);
        const float inv = 1.f / lt;
        const size_t obase = ((size_t)(b_ * S + qtb * BT + srow)) * HID + h_ * 64 + quad * 4;
        #pragma unroll
        for (int jn = 0; jn < 4; ++jn) {
            union { bf16 h4[4]; bf16x4 v4; } u;
            #pragma unroll
            for (int r = 0; r < 4; ++r)
                u.h4[r] = __float2bfloat16(otb[jn][r] * inv);
            *(bf16x4*)&og[obase + jn * 16] = u.v4;
        }
    }
    {
        float lt = la;
        lt += __shfl_xor(lt, 16);
        lt += __shfl_xor(lt, 32);
        const float inv = 1.f / lt;
        const size_t obase = ((size_t)(b_ * S + qta * BT + srow)) * HID + h_ * 64 + quad * 4;
        #pragma unroll
        for (int jn = 0; jn < 4; ++jn) {
            union { bf16 h4[4]; bf16x4 v4; } u;
            #pragma unroll
            for (int r = 0; r < 4; ++r)
                u.h4[r] = __float2bfloat16(ota[jn][r] * inv);
            *(bf16x4*)&og[obase + jn * 16] = u.v4;
        }
    }
}

// ---------------------------------------------------------------------------
// Kernel 3: output projection — R25 dbuf body (kept).
// ---------------------------------------------------------------------------
__global__ __launch_bounds__(256) void out_proj_mfma_kernel(
    const bf16* __restrict__ o, const float* __restrict__ Wo,
    const float* __restrict__ bo, float* __restrict__ out)
{
    __shared__ bf16 Os[2][32 * QSTR];
    __shared__ bf16 Wot[2][64 * QSTR];
    __shared__ float bos[64];

    const int tid = threadIdx.x;
    const int m0  = blockIdx.x * 32;
    const int lane = tid & 63, wave = tid >> 6;
    const int c = lane & 15, quad = lane >> 4;
    const int mtile = wave >> 1;
    const int ngb   = (wave & 1) * 2;

    const int orow = tid >> 3, ooct = tid & 7;
    const int n0 = (tid & 15) * 4, kk0 = (tid >> 4) * 4;

    if (tid < 64) bos[tid] = bo[tid];

    bf16x8 oreg = *(const bf16x8*)(o + (size_t)(m0 + orow) * HID + ooct * 8);
    float4 w4[4];
    #pragma unroll
    for (int j = 0; j < 4; ++j)
        w4[j] = *(const float4*)&Wo[(size_t)(kk0 + j) * 64 + n0];

    auto stage = [&](int buf) {
        *(bf16x8*)&Os[buf][orow * QSTR + ooct * 8] = oreg;
        #pragma unroll
        for (int dn = 0; dn < 4; ++dn) {
            union { bf16 h[4]; bf16x4 v4; } u;
            u.h[0] = __float2bfloat16((&w4[0].x)[dn]);
            u.h[1] = __float2bfloat16((&w4[1].x)[dn]);
            u.h[2] = __float2bfloat16((&w4[2].x)[dn]);
            u.h[3] = __float2bfloat16((&w4[3].x)[dn]);
            *(bf16x4*)&Wot[buf][(n0 + dn) * QSTR + kk0] = u.v4;
        }
    };

    // prologue: stage chunk 0 into buf 0, prefetch chunk 1 into regs
    stage(0);
    {
        const int k1 = 64;
        oreg = *(const bf16x8*)(o + (size_t)(m0 + orow) * HID + k1 + ooct * 8);
        #pragma unroll
        for (int j = 0; j < 4; ++j)
            w4[j] = *(const float4*)&Wo[(size_t)(k1 + kk0 + j) * 64 + n0];
    }
    __syncthreads();

    f32x4 acc[2];
    acc[0] = (f32x4){0.f, 0.f, 0.f, 0.f};
    acc[1] = (f32x4){0.f, 0.f, 0.f, 0.f};

    int cur = 0;
    for (int chunk = 0; chunk < 16; ++chunk) {
        // stage next chunk into the freed buffer, refill regs with chunk+2
        if (chunk < 15) {
            stage(cur ^ 1);
            if (chunk + 1 < 15) {
                const int k2 = (chunk + 2) * 64;
                oreg = *(const bf16x8*)(o + (size_t)(m0 + orow) * HID + k2 + ooct * 8);
                #pragma unroll
                for (int j = 0; j < 4; ++j)
                    w4[j] = *(const float4*)&Wo[(size_t)(k2 + kk0 + j) * 64 + n0];
            }
        }

        bf16x8 a0 = *(const bf16x8*)&Os[cur][(mtile * 16 + c) * QSTR + quad * 8];
        bf16x8 a1 = *(const bf16x8*)&Os[cur][(mtile * 16 + c) * QSTR + 32 + quad * 8];
        #pragma unroll
        for (int g = 0; g < 2; ++g) {
            int ng = ngb + g;
            bf16x8 b0 = *(const bf16x8*)&Wot[cur][(ng * 16 + c) * QSTR + quad * 8];
            bf16x8 b1 = *(const bf16x8*)&Wot[cur][(ng * 16 + c) * QSTR + 32 + quad * 8];
            acc[g] = __builtin_amdgcn_mfma_f32_16x16x32_bf16(a0, b0, acc[g], 0, 0, 0);
            acc[g] = __builtin_amdgcn_mfma_f32_16x16x32_bf16(a1, b1, acc[g], 0, 0, 0);
        }

        if (chunk < 15) {
            __syncthreads();
            cur ^= 1;
        }
    }

    #pragma unroll
    for (int g = 0; g < 2; ++g) {
        int n = (ngb + g) * 16 + c;
        float bb_ = bos[n];
        #pragma unroll
        for (int r = 0; r < 4; ++r) {
            int row = m0 + mtile * 16 + quad * 4 + r;
            out[(size_t)row * 64 + n] = acc[g][r] + bb_;
        }
    }
}

// ---------------------------------------------------------------------------
extern "C" void kernel_launch(void* const* d_in, const int* in_sizes, int n_in,
                              void* d_out, int out_size, void* d_ws, size_t ws_size,
                              hipStream_t stream)
{
    const float* x  = (const float*)d_in[0];
    const float* Wq = (const float*)d_in[1];
    const float* bq = (const float*)d_in[2];
    const float* Wk = (const float*)d_in[3];
    const float* bk = (const float*)d_in[4];
    const float* Wv = (const float*)d_in[5];
    const float* bv = (const float*)d_in[6];
    const float* Wo = (const float*)d_in[7];
    const float* bo = (const float*)d_in[8];

    char* ws = (char*)d_ws;
    const size_t qkv_bytes = (size_t)B * S * HID * sizeof(bf16);  // 16 MiB each
    bf16* qw = (bf16*)(ws);
    bf16* kw = (bf16*)(ws + qkv_bytes);
    bf16* vw = (bf16*)(ws + 2 * qkv_bytes);   // transposed [B][H][D][S]
    bf16* ow = (bf16*)(ws + 3 * qkv_bytes);

    qkv_mfma_kernel<<<dim3(B * S / 128, 24), 256, 0, stream>>>(
        x, Wq, bq, Wk, bk, Wv, bv, qw, kw, vw);

    flash_mfma_kernel<<<dim3(8, B * H), 512, 0, stream>>>(qw, kw, vw, ow);

    out_proj_mfma_kernel<<<dim3(B * S / 32), 256, 0, stream>>>(ow, Wo, bo,
                                                               (float*)d_out);
}